// Round 2
// baseline (167.466 us; speedup 1.0000x reference)
//
#include <hip/hip_runtime.h>

typedef unsigned short ushort_t;
typedef unsigned int   uint_t;

typedef __attribute__((ext_vector_type(8))) short  short8;   // 8 bf16 in 4 VGPRs
typedef __attribute__((ext_vector_type(4))) short  short4v;  // 4 bf16 (b64)
typedef __attribute__((ext_vector_type(4))) float  float4v;  // MFMA 16x16 acc

#define BB    8
#define CC    256
#define HH    64
#define WW2   64
#define NPIX  4096   // H*W
#define MPOS  1024   // (H/2)*(W/2)
#define ICH   64

__device__ __forceinline__ float bf2f(ushort_t u) {
  return __uint_as_float(((uint_t)u) << 16);
}
__device__ __forceinline__ ushort_t f2bf(float f) {
  uint_t i = __float_as_uint(f);
  uint_t r = (i + 0x7FFFu + ((i >> 16) & 1u)) >> 16;  // RNE
  return (ushort_t)r;
}
__device__ __forceinline__ ushort_t f2bf_rna(float f) {   // cheap round-half-away
  return (ushort_t)((__float_as_uint(f) + 0x8000u) >> 16);
}
__device__ __forceinline__ uint_t pack2(float a, float b) {
  return (uint_t)f2bf(a) | ((uint_t)f2bf(b) << 16);
}

// ---------------------------------------------------------------------------
// K0: weight prep into coalesced-fragment layouts (unchanged):
//   wA2 [32 kblk][192 o][8 k], Wbf2 [8 icblk][256 o][8 ic], biasAll [192] f32
// ---------------------------------------------------------------------------
__global__ __launch_bounds__(256) void prep_kernel(
    const float* __restrict__ theta_w, const float* __restrict__ phi_w,
    const float* __restrict__ g_w, const float* __restrict__ W_w,
    const float* __restrict__ theta_b, const float* __restrict__ phi_b,
    const float* __restrict__ g_b,
    ushort_t* __restrict__ wA2, ushort_t* __restrict__ Wbf2,
    float* __restrict__ biasAll) {
  int i = blockIdx.x * 256 + threadIdx.x;
  if (i < 49152) {         // theta|phi|g -> wA2
    float v = (i < 16384) ? theta_w[i]
            : (i < 32768) ? phi_w[i - 16384]
                          : g_w[i - 32768];
    int o = i >> 8, c = i & 255;
    wA2[(c >> 3) * 1536 + o * 8 + (c & 7)] = f2bf(v);
  } else if (i < 65536) {  // W_w -> Wbf2
    int j = i - 49152;
    int o = j >> 6, ic = j & 63;
    Wbf2[(ic >> 3) * 2048 + o * 8 + (ic & 7)] = f2bf(W_w[j]);
  } else if (i < 65600)    biasAll[i - 65536] = theta_b[i - 65536];
  else if (i < 65664)      biasAll[i - 65536] = phi_b[i - 65600];
  else if (i < 65728)      biasAll[i - 65536] = g_b[i - 65664];
}

// ---------------------------------------------------------------------------
// K1: q/k/v conv GEMM + 2x2 maxpool (reverted to known-best r0 baseline).
// Grid 512 = 8 b x 32 row-pairs x 2 col-halves; tile = 64 pixels,
// K=256 fully resident in LDS. ONE barrier, then M=192 x N=64 x K=256 MFMA.
// ---------------------------------------------------------------------------
__global__ __launch_bounds__(256, 2) void qkv_kernel(
    const float* __restrict__ x, const ushort_t* __restrict__ wA2,
    const float* __restrict__ biasAll,
    ushort_t* __restrict__ qbuf, ushort_t* __restrict__ kTbuf,
    ushort_t* __restrict__ vTbuf) {
  __shared__ __align__(16) ushort_t Bsu[64 * 256];
  uint4* Bs16 = (uint4*)Bsu;
  int tid = threadIdx.x;
  int wave = tid >> 6, lane = tid & 63;
  int quad = lane >> 4, col = lane & 15;
  int b = blockIdx.x >> 6, t = blockIdx.x & 63;
  int rj = t >> 1, h = t & 1;

  // ---- stage x tile: thread covers pixel `pos`, channels [cg*64, cg*64+64)
  {
    int pos = tid & 63, cg = tid >> 6;
    int prow = pos >> 5, pcol = pos & 31;
    const float* xsrc = x + (size_t)b * (CC * NPIX) +
                        (size_t)(2 * rj + prow) * WW2 + h * 32 + pcol;
#pragma unroll
    for (int g = 0; g < 8; ++g) {
      float v[8];
#pragma unroll
      for (int j = 0; j < 8; ++j)
        v[j] = xsrc[(size_t)(cg * 64 + g * 8 + j) * NPIX];
      uint4 w;
      w.x = pack2(v[0], v[1]);
      w.y = pack2(v[2], v[3]);
      w.z = pack2(v[4], v[5]);
      w.w = pack2(v[6], v[7]);
      int jb = cg * 8 + g;  // 16B-block index in K (0..31)
      Bs16[pos * 32 + (jb & ~7) + ((jb & 7) ^ (pos & 7))] = w;
    }
  }
  __syncthreads();

  float4v acc[3][4];
#pragma unroll
  for (int ot = 0; ot < 3; ++ot) {
    int ob = wave * 48 + ot * 16 + quad * 4;
    float4v bv;
#pragma unroll
    for (int r = 0; r < 4; ++r) bv[r] = biasAll[ob + r];
#pragma unroll
    for (int s = 0; s < 4; ++s) acc[ot][s] = bv;
  }

  const uint4* wA16 = (const uint4*)wA2;
#pragma unroll
  for (int ks = 0; ks < 8; ++ks) {
    int kblk = ks * 4 + quad;               // 16B-block index in K (0..31)
    short8 aw[3];
#pragma unroll
    for (int ot = 0; ot < 3; ++ot) {
      uint4 a = wA16[kblk * 192 + wave * 48 + ot * 16 + col];
      aw[ot] = *(const short8*)&a;
    }
#pragma unroll
    for (int s = 0; s < 4; ++s) {
      int lp = s * 16 + col;
      uint4 braw = Bs16[lp * 32 + (kblk & ~7) + ((kblk & 7) ^ (lp & 7))];
      short8 bx = *(const short8*)&braw;
#pragma unroll
      for (int ot = 0; ot < 3; ++ot)
        acc[ot][s] = __builtin_amdgcn_mfma_f32_16x16x32_bf16(aw[ot], bx, acc[ot][s], 0, 0, 0);
    }
  }

  // epilogue: lane value (o = ob+quad*4+r, lp = s*16+col)
#pragma unroll
  for (int ot = 0; ot < 3; ++ot) {
    int ob = wave * 48 + ot * 16;
    if (ob < 64) {  // theta -> qbuf[b][n][o]
#pragma unroll
      for (int s = 0; s < 4; ++s) {
        int n = (2 * rj + (s >> 1)) * WW2 + h * 32 + (s & 1) * 16 + col;
        uint2 u;
        u.x = pack2(acc[ot][s][0], acc[ot][s][1]);
        u.y = pack2(acc[ot][s][2], acc[ot][s][3]);
        *(uint2*)&qbuf[((size_t)(b * NPIX + n)) * ICH + ob + quad * 4] = u;
      }
    } else if (ob < 128) {  // phi -> pool -> kTbuf[b][m][ic]
#pragma unroll
      for (int s = 0; s < 2; ++s) {
        float4v pm;
#pragma unroll
        for (int r = 0; r < 4; ++r) {
          float v = fmaxf(acc[ot][s][r], acc[ot][s + 2][r]);
          pm[r] = fmaxf(v, __shfl_xor(v, 1));
        }
        if ((lane & 1) == 0) {
          int m = rj * 32 + h * 16 + s * 8 + (col >> 1);
          uint2 u;
          u.x = pack2(pm[0], pm[1]);
          u.y = pack2(pm[2], pm[3]);
          *(uint2*)&kTbuf[((size_t)(b * MPOS + m)) * ICH + (ob - 64) + quad * 4] = u;
        }
      }
    } else {  // g -> pool -> vTbuf[b][ic][m]
#pragma unroll
      for (int s = 0; s < 2; ++s) {
        float4v pm;
#pragma unroll
        for (int r = 0; r < 4; ++r) {
          float v = fmaxf(acc[ot][s][r], acc[ot][s + 2][r]);
          pm[r] = fmaxf(v, __shfl_xor(v, 1));
        }
        if ((lane & 1) == 0) {
          int m = rj * 32 + h * 16 + s * 8 + (col >> 1);
#pragma unroll
          for (int r = 0; r < 4; ++r)
            vTbuf[((size_t)(b * ICH + (ob - 128) + quad * 4 + r)) * MPOS + m] = f2bf(pm[r]);
        }
      }
    }
  }
}

// ---------------------------------------------------------------------------
// K2: FUSED attention + output conv + residual — BARRIER-FREE, per-wave
// independent. Each wave owns 16 query rows and loops over all 1024 keys.
// K/V for one batch is 2 MB (L2/L3-resident) and the kTbuf[b][m][ic] /
// vTbuf[b][ic][m] layouts are exactly MFMA B-fragment order, so fragments
// are loaded DIRECTLY from global as contiguous 16B vectors: no LDS staging,
// no swizzles, zero __syncthreads. K-frags are register-double-buffered one
// iteration ahead; V-frags issue at the top of each iteration and are used
// after QK+exp (~1k cycles of covering work). Only LDS use: 2.3 KB/wave
// wave-private P round-trip (same-wave DS ordering, no barrier).
// Grid 512 x 256 (2 blocks/CU, 2 waves/SIMD, fully independent waves).
// ---------------------------------------------------------------------------
__global__ __launch_bounds__(256, 2) void attn_out_kernel(
    const ushort_t* __restrict__ qbuf, const ushort_t* __restrict__ kTbuf,
    const ushort_t* __restrict__ vTbuf, const ushort_t* __restrict__ Wbf2,
    const float* __restrict__ W_b, const float* __restrict__ x,
    float* __restrict__ out) {
  __shared__ __align__(16) ushort_t Ps[4][16 * 72];
  int tid  = threadIdx.x;
  int wid  = tid >> 6, lane = tid & 63;
  int quad = lane >> 4, col = lane & 15;
  int job  = blockIdx.x * 4 + wid;   // 0..2047 ; consecutive jobs same batch
  int b    = job >> 8;
  int qbase = (job & 255) * 16;

  ushort_t* Psw = &Ps[wid][0];       // wave-private [16][72]

  const ushort_t* kb = kTbuf + (size_t)b * MPOS * ICH;
  const ushort_t* vb = vTbuf + (size_t)b * ICH * MPOS;

  // Q A-frags (one-time)
  const ushort_t* qrow = qbuf + ((size_t)(b * NPIX + qbase + col)) * ICH;
  short8 aQ0 = *(const short8*)&qrow[quad * 8];
  short8 aQ1 = *(const short8*)&qrow[32 + quad * 8];

  // per-lane fragment base pointers (all further offsets compile-time or kt)
  const ushort_t* kbase = kb + col * ICH + quad * 8;    // + (kt*64+t*16)*64 (+32)
  const ushort_t* vbase = vb + (size_t)col * MPOS + quad * 8; // + t*16*MPOS + kt*64 + kk*32

  const float4v zero4 = {0.f, 0.f, 0.f, 0.f};
  float l_lane[4] = {0.f, 0.f, 0.f, 0.f};
  float4v o_acc[4];
#pragma unroll
  for (int t = 0; t < 4; ++t) o_acc[t] = zero4;

  short8 kfA[8], kfB[8];

#define LOADK(dst, kt)                                                        \
  _Pragma("unroll")                                                           \
  for (int t = 0; t < 4; ++t) {                                               \
    dst[t * 2 + 0] = *(const short8*)&kbase[((kt) * 64 + t * 16) * 64];       \
    dst[t * 2 + 1] = *(const short8*)&kbase[((kt) * 64 + t * 16) * 64 + 32];  \
  }

  LOADK(kfA, 0);

#define STEP(kcur, knext, kt)                                                 \
  {                                                                           \
    short8 vf[8];                                                             \
    _Pragma("unroll")                                                         \
    for (int t = 0; t < 4; ++t) {                                             \
      _Pragma("unroll")                                                       \
      for (int kk = 0; kk < 2; ++kk)                                          \
        vf[t * 2 + kk] =                                                      \
            *(const short8*)&vbase[t * 16 * MPOS + (kt) * 64 + kk * 32];      \
    }                                                                         \
    if ((kt) < 15) { LOADK(knext, (kt) + 1); }                                \
    float4v s_acc[4];                                                         \
    __builtin_amdgcn_s_setprio(1);                                            \
    _Pragma("unroll")                                                         \
    for (int t = 0; t < 4; ++t) {                                             \
      float4v s = zero4;                                                      \
      s = __builtin_amdgcn_mfma_f32_16x16x32_bf16(aQ0, kcur[t * 2 + 0], s, 0, 0, 0); \
      s = __builtin_amdgcn_mfma_f32_16x16x32_bf16(aQ1, kcur[t * 2 + 1], s, 0, 0, 0); \
      s_acc[t] = s;                                                           \
    }                                                                         \
    __builtin_amdgcn_s_setprio(0);                                            \
    _Pragma("unroll")                                                         \
    for (int r = 0; r < 4; ++r) {                                             \
      int prow = (quad * 4 + r) * 72;                                         \
      _Pragma("unroll")                                                       \
      for (int t = 0; t < 4; ++t) {                                           \
        float pv = __expf(s_acc[t][r]);                                       \
        l_lane[r] += pv;                                                      \
        Psw[prow + t * 16 + col] = f2bf_rna(pv);                              \
      }                                                                       \
    }                                                                         \
    __builtin_amdgcn_s_setprio(1);                                            \
    _Pragma("unroll")                                                         \
    for (int kk = 0; kk < 2; ++kk) {                                          \
      short8 ap = *(const short8*)&Psw[col * 72 + kk * 32 + quad * 8];        \
      _Pragma("unroll")                                                       \
      for (int t = 0; t < 4; ++t)                                             \
        o_acc[t] = __builtin_amdgcn_mfma_f32_16x16x32_bf16(ap, vf[t * 2 + kk], o_acc[t], 0, 0, 0); \
    }                                                                         \
    __builtin_amdgcn_s_setprio(0);                                            \
  }

  for (int i = 0; i < 8; ++i) {
    STEP(kfA, kfB, 2 * i);
    STEP(kfB, kfA, 2 * i + 1);
  }
#undef STEP
#undef LOADK

  // ---- normalize: l reduce over 16 cols, write attended rows (bf16) into
  // wave-private Ps rows (same-wave DS ordering -> no barrier).
#pragma unroll
  for (int r = 0; r < 4; ++r) {
    float l = l_lane[r];
    l += __shfl_xor(l, 1);
    l += __shfl_xor(l, 2);
    l += __shfl_xor(l, 4);
    l += __shfl_xor(l, 8);
    float inv = 1.0f / l;
    int prow = (quad * 4 + r) * 72;
#pragma unroll
    for (int t = 0; t < 4; ++t)
      Psw[prow + t * 16 + col] = f2bf(o_acc[t][r] * inv);
  }

  // ---- fused output conv: D[p=16][o=256] + residual, per wave
  short8 ap0 = *(const short8*)&Psw[col * 72 + quad * 8];
  short8 ap1 = *(const short8*)&Psw[col * 72 + 32 + quad * 8];
  const uint4* W16 = (const uint4*)Wbf2;
  int pbase = qbase + quad * 4;
#pragma unroll
  for (int ot = 0; ot < 16; ++ot) {
    float bvv = W_b[ot * 16 + col];
    float4v c = {bvv, bvv, bvv, bvv};
    uint4 w0 = W16[quad * 256 + ot * 16 + col];
    uint4 w1 = W16[(4 + quad) * 256 + ot * 16 + col];
    c = __builtin_amdgcn_mfma_f32_16x16x32_bf16(ap0, *(const short8*)&w0, c, 0, 0, 0);
    c = __builtin_amdgcn_mfma_f32_16x16x32_bf16(ap1, *(const short8*)&w1, c, 0, 0, 0);
    size_t idx = ((size_t)(b * CC + ot * 16 + col)) * NPIX + pbase;
    float4 xv = *(const float4*)&x[idx];
    float4 ov;
    ov.x = c[0] + xv.x;
    ov.y = c[1] + xv.y;
    ov.z = c[2] + xv.z;
    ov.w = c[3] + xv.w;
    *(float4*)&out[idx] = ov;
  }
}

// ---------------------------------------------------------------------------
extern "C" void kernel_launch(void* const* d_in, const int* in_sizes, int n_in,
                              void* d_out, int out_size, void* d_ws, size_t ws_size,
                              hipStream_t stream) {
  const float* x       = (const float*)d_in[0];
  const float* g_w     = (const float*)d_in[1];
  const float* g_b     = (const float*)d_in[2];
  const float* theta_w = (const float*)d_in[3];
  const float* theta_b = (const float*)d_in[4];
  const float* phi_w   = (const float*)d_in[5];
  const float* phi_b   = (const float*)d_in[6];
  const float* W_w     = (const float*)d_in[7];
  const float* W_b     = (const float*)d_in[8];
  (void)in_sizes; (void)n_in; (void)out_size; (void)ws_size;

  char* ws = (char*)d_ws;
  ushort_t* wA2     = (ushort_t*)(ws + 0);         // 96KB bf16 [32][192][8]
  ushort_t* Wbf2    = (ushort_t*)(ws + 98304);     // 32KB bf16 [8][256][8]
  float*    biasAll = (float*)(ws + 131072);       // 768B
  ushort_t* qbuf    = (ushort_t*)(ws + 262144);    // 4MB bf16 [8][4096][64]
  ushort_t* kTbuf   = (ushort_t*)(ws + 4456448);   // 1MB bf16 [8][1024][64]
  ushort_t* vTbuf   = (ushort_t*)(ws + 5505024);   // 1MB bf16 [8][64][1024]
  float* out = (float*)d_out;

  prep_kernel<<<257, 256, 0, stream>>>(theta_w, phi_w, g_w, W_w,
                                       theta_b, phi_b, g_b,
                                       wA2, Wbf2, biasAll);
  qkv_kernel<<<512, 256, 0, stream>>>(x, wA2, biasAll, qbuf, kTbuf, vTbuf);
  attn_out_kernel<<<512, 256, 0, stream>>>(qbuf, kTbuf, vTbuf, Wbf2, W_b, x, out);
}

// Round 3
// 131.079 us; speedup vs baseline: 1.2776x; 1.2776x over previous
//
#include <hip/hip_runtime.h>

typedef unsigned short ushort_t;
typedef unsigned int   uint_t;

typedef __attribute__((ext_vector_type(8))) short  short8;   // 8 bf16 in 4 VGPRs
typedef __attribute__((ext_vector_type(4))) short  short4v;  // 4 bf16 (b64)
typedef __attribute__((ext_vector_type(4))) float  float4v;  // MFMA 16x16 acc

#define BB    8
#define CC    256
#define HH    64
#define WW2   64
#define NPIX  4096   // H*W
#define MPOS  1024   // (H/2)*(W/2)
#define ICH   64

__device__ __forceinline__ float bf2f(ushort_t u) {
  return __uint_as_float(((uint_t)u) << 16);
}
__device__ __forceinline__ ushort_t f2bf(float f) {
  uint_t i = __float_as_uint(f);
  uint_t r = (i + 0x7FFFu + ((i >> 16) & 1u)) >> 16;  // RNE
  return (ushort_t)r;
}
__device__ __forceinline__ ushort_t f2bf_rna(float f) {   // cheap round-half-away
  return (ushort_t)((__float_as_uint(f) + 0x8000u) >> 16);
}
__device__ __forceinline__ uint_t pack2(float a, float b) {
  return (uint_t)f2bf(a) | ((uint_t)f2bf(b) << 16);
}

// async global->LDS, 16B per lane; LDS dest = wave-uniform base + lane*16
__device__ __forceinline__ void gl2lds16(const ushort_t* g, ushort_t* l) {
  __builtin_amdgcn_global_load_lds(
      (const __attribute__((address_space(1))) void*)g,
      (__attribute__((address_space(3))) void*)l, 16, 0, 0);
}

// ---------------------------------------------------------------------------
// K0: weight prep into coalesced-fragment layouts (unchanged):
//   wA2 [32 kblk][192 o][8 k], Wbf2 [8 icblk][256 o][8 ic], biasAll [192] f32
// ---------------------------------------------------------------------------
__global__ __launch_bounds__(256) void prep_kernel(
    const float* __restrict__ theta_w, const float* __restrict__ phi_w,
    const float* __restrict__ g_w, const float* __restrict__ W_w,
    const float* __restrict__ theta_b, const float* __restrict__ phi_b,
    const float* __restrict__ g_b,
    ushort_t* __restrict__ wA2, ushort_t* __restrict__ Wbf2,
    float* __restrict__ biasAll) {
  int i = blockIdx.x * 256 + threadIdx.x;
  if (i < 49152) {         // theta|phi|g -> wA2
    float v = (i < 16384) ? theta_w[i]
            : (i < 32768) ? phi_w[i - 16384]
                          : g_w[i - 32768];
    int o = i >> 8, c = i & 255;
    wA2[(c >> 3) * 1536 + o * 8 + (c & 7)] = f2bf(v);
  } else if (i < 65536) {  // W_w -> Wbf2
    int j = i - 49152;
    int o = j >> 6, ic = j & 63;
    Wbf2[(ic >> 3) * 2048 + o * 8 + (ic & 7)] = f2bf(W_w[j]);
  } else if (i < 65600)    biasAll[i - 65536] = theta_b[i - 65536];
  else if (i < 65664)      biasAll[i - 65536] = phi_b[i - 65600];
  else if (i < 65728)      biasAll[i - 65536] = g_b[i - 65664];
}

// ---------------------------------------------------------------------------
// K1: q/k/v conv GEMM + 2x2 maxpool (r0 baseline, unchanged).
// Grid 512 = 8 b x 32 row-pairs x 2 col-halves; tile = 64 pixels,
// K=256 fully resident in LDS. ONE barrier, then M=192 x N=64 x K=256 MFMA.
// ---------------------------------------------------------------------------
__global__ __launch_bounds__(256, 2) void qkv_kernel(
    const float* __restrict__ x, const ushort_t* __restrict__ wA2,
    const float* __restrict__ biasAll,
    ushort_t* __restrict__ qbuf, ushort_t* __restrict__ kTbuf,
    ushort_t* __restrict__ vTbuf) {
  __shared__ __align__(16) ushort_t Bsu[64 * 256];
  uint4* Bs16 = (uint4*)Bsu;
  int tid = threadIdx.x;
  int wave = tid >> 6, lane = tid & 63;
  int quad = lane >> 4, col = lane & 15;
  int b = blockIdx.x >> 6, t = blockIdx.x & 63;
  int rj = t >> 1, h = t & 1;

  // ---- stage x tile: thread covers pixel `pos`, channels [cg*64, cg*64+64)
  {
    int pos = tid & 63, cg = tid >> 6;
    int prow = pos >> 5, pcol = pos & 31;
    const float* xsrc = x + (size_t)b * (CC * NPIX) +
                        (size_t)(2 * rj + prow) * WW2 + h * 32 + pcol;
#pragma unroll
    for (int g = 0; g < 8; ++g) {
      float v[8];
#pragma unroll
      for (int j = 0; j < 8; ++j)
        v[j] = xsrc[(size_t)(cg * 64 + g * 8 + j) * NPIX];
      uint4 w;
      w.x = pack2(v[0], v[1]);
      w.y = pack2(v[2], v[3]);
      w.z = pack2(v[4], v[5]);
      w.w = pack2(v[6], v[7]);
      int jb = cg * 8 + g;  // 16B-block index in K (0..31)
      Bs16[pos * 32 + (jb & ~7) + ((jb & 7) ^ (pos & 7))] = w;
    }
  }
  __syncthreads();

  float4v acc[3][4];
#pragma unroll
  for (int ot = 0; ot < 3; ++ot) {
    int ob = wave * 48 + ot * 16 + quad * 4;
    float4v bv;
#pragma unroll
    for (int r = 0; r < 4; ++r) bv[r] = biasAll[ob + r];
#pragma unroll
    for (int s = 0; s < 4; ++s) acc[ot][s] = bv;
  }

  const uint4* wA16 = (const uint4*)wA2;
#pragma unroll
  for (int ks = 0; ks < 8; ++ks) {
    int kblk = ks * 4 + quad;               // 16B-block index in K (0..31)
    short8 aw[3];
#pragma unroll
    for (int ot = 0; ot < 3; ++ot) {
      uint4 a = wA16[kblk * 192 + wave * 48 + ot * 16 + col];
      aw[ot] = *(const short8*)&a;
    }
#pragma unroll
    for (int s = 0; s < 4; ++s) {
      int lp = s * 16 + col;
      uint4 braw = Bs16[lp * 32 + (kblk & ~7) + ((kblk & 7) ^ (lp & 7))];
      short8 bx = *(const short8*)&braw;
#pragma unroll
      for (int ot = 0; ot < 3; ++ot)
        acc[ot][s] = __builtin_amdgcn_mfma_f32_16x16x32_bf16(aw[ot], bx, acc[ot][s], 0, 0, 0);
    }
  }

  // epilogue: lane value (o = ob+quad*4+r, lp = s*16+col)
#pragma unroll
  for (int ot = 0; ot < 3; ++ot) {
    int ob = wave * 48 + ot * 16;
    if (ob < 64) {  // theta -> qbuf[b][n][o]
#pragma unroll
      for (int s = 0; s < 4; ++s) {
        int n = (2 * rj + (s >> 1)) * WW2 + h * 32 + (s & 1) * 16 + col;
        uint2 u;
        u.x = pack2(acc[ot][s][0], acc[ot][s][1]);
        u.y = pack2(acc[ot][s][2], acc[ot][s][3]);
        *(uint2*)&qbuf[((size_t)(b * NPIX + n)) * ICH + ob + quad * 4] = u;
      }
    } else if (ob < 128) {  // phi -> pool -> kTbuf[b][m][ic]
#pragma unroll
      for (int s = 0; s < 2; ++s) {
        float4v pm;
#pragma unroll
        for (int r = 0; r < 4; ++r) {
          float v = fmaxf(acc[ot][s][r], acc[ot][s + 2][r]);
          pm[r] = fmaxf(v, __shfl_xor(v, 1));
        }
        if ((lane & 1) == 0) {
          int m = rj * 32 + h * 16 + s * 8 + (col >> 1);
          uint2 u;
          u.x = pack2(pm[0], pm[1]);
          u.y = pack2(pm[2], pm[3]);
          *(uint2*)&kTbuf[((size_t)(b * MPOS + m)) * ICH + (ob - 64) + quad * 4] = u;
        }
      }
    } else {  // g -> pool -> vTbuf[b][ic][m]
#pragma unroll
      for (int s = 0; s < 2; ++s) {
        float4v pm;
#pragma unroll
        for (int r = 0; r < 4; ++r) {
          float v = fmaxf(acc[ot][s][r], acc[ot][s + 2][r]);
          pm[r] = fmaxf(v, __shfl_xor(v, 1));
        }
        if ((lane & 1) == 0) {
          int m = rj * 32 + h * 16 + s * 8 + (col >> 1);
#pragma unroll
          for (int r = 0; r < 4; ++r)
            vTbuf[((size_t)(b * ICH + (ob - 128) + quad * 4 + r)) * MPOS + m] = f2bf(pm[r]);
        }
      }
    }
  }
}

// ---------------------------------------------------------------------------
// K2: FUSED attention + output conv + residual. r0 structure (LDS-staged
// double-buffered K/V, one barrier/kt) with two surgical changes:
//  (a) staging via global_load_lds (16B DMA): LINEAR LDS dest, XOR-swizzle
//      moved to the pre-swizzled GLOBAL source address; issued at the TOP of
//      each iteration into the other buffer (async under the whole body).
//  (b) QK^T computed operand-swapped: D[key][q] puts 4 consecutive keys per
//      lane, so P-writes are 4x uint2 (8B) stores instead of 16x u16, and
//      the softmax denominator reduces with 2 shuffles. PV side unchanged.
// S, P, PV are bitwise identical to r0; only l's f32 summation grouping
// changes. LDS 41 KB, grid 512 x 256, 2 blocks/CU.
// ---------------------------------------------------------------------------
__global__ __launch_bounds__(256, 2) void attn_out_kernel(
    const ushort_t* __restrict__ qbuf, const ushort_t* __restrict__ kTbuf,
    const ushort_t* __restrict__ vTbuf, const ushort_t* __restrict__ Wbf2,
    const float* __restrict__ W_b, const float* __restrict__ x,
    float* __restrict__ out) {
  __shared__ __align__(16) ushort_t Ks[2][64 * 64];
  __shared__ __align__(16) ushort_t Vs[2][64 * 64];
  __shared__ __align__(16) ushort_t Ps[4][16 * 72];
  int tid  = threadIdx.x;
  int wave = tid >> 6, lane = tid & 63;
  int quad = lane >> 4, col = lane & 15;
  int b = blockIdx.x >> 6, qt = blockIdx.x & 63;

  ushort_t* Psw = &Ps[wave][0];       // wave-private [16][72]

  // Q fragments (B-operand of swapped QK; same bytes as r0's A-frags)
  const ushort_t* qrow = qbuf + ((size_t)(b * NPIX + qt * 64 + wave * 16 + col)) * ICH;
  short8 aQ0 = *(const short8*)&qrow[quad * 8];
  short8 aQ1 = *(const short8*)&qrow[32 + quad * 8];

  // staging: thread stages rows {srow, srow+32} of the K-tile and V-tile,
  // one 16B block each; source block index pre-swizzled so the linear DMA
  // dest (base + lane*16) realizes the same LDS image as r0's swizzled
  // ds_writes. (32+srow)&7 == srow&7, so one swz serves both rows.
  int srow = tid >> 3, sblk = tid & 7;
  int swz  = (sblk ^ (srow & 7)) * 8;                    // element offset
  const ushort_t* kg = kTbuf + (size_t)b * MPOS * ICH;   // row m: 64 elems
  const ushort_t* vg = vTbuf + (size_t)b * ICH * MPOS;   // row ic: 1024 elems
  const ushort_t* kg0 = kg + srow * ICH + swz;           // + kt*4096
  const ushort_t* kg1 = kg + (32 + srow) * ICH + swz;
  const ushort_t* vg0 = vg + (size_t)srow * MPOS + swz;  // + kt*64
  const ushort_t* vg1 = vg + (size_t)(32 + srow) * MPOS + swz;

#define STAGE(bufi, kt)                                          \
  do {                                                           \
    gl2lds16(kg0 + (kt) * 4096, &Ks[bufi][wave * 512]);          \
    gl2lds16(kg1 + (kt) * 4096, &Ks[bufi][2048 + wave * 512]);   \
    gl2lds16(vg0 + (kt) * 64,   &Vs[bufi][wave * 512]);          \
    gl2lds16(vg1 + (kt) * 64,   &Vs[bufi][2048 + wave * 512]);   \
  } while (0)

  STAGE(0, 0);
  __syncthreads();

  const float4v zero4 = {0.f, 0.f, 0.f, 0.f};
  float l_lane = 0.f;                  // denominator partial for q = col
  float4v o_acc[4];
#pragma unroll
  for (int t = 0; t < 4; ++t) o_acc[t] = zero4;

  for (int kt = 0; kt < 16; ++kt) {
    int buf = kt & 1;
    if (kt < 15) STAGE(buf ^ 1, kt + 1);   // async DMA under this iteration

    // S^T = K . Q^T : s_acc[t][r] = S[key=t*16+quad*4+r][q=col]
    float4v s_acc[4];
    __builtin_amdgcn_s_setprio(1);
#pragma unroll
    for (int t = 0; t < 4; ++t) {
      float4v s = zero4;
      short8 ak0 = *(const short8*)&Ks[buf][(t * 16 + col) * 64 + ((quad ^ (col & 7)) * 8)];
      s = __builtin_amdgcn_mfma_f32_16x16x32_bf16(ak0, aQ0, s, 0, 0, 0);
      short8 ak1 = *(const short8*)&Ks[buf][(t * 16 + col) * 64 + (((4 + quad) ^ (col & 7)) * 8)];
      s = __builtin_amdgcn_mfma_f32_16x16x32_bf16(ak1, aQ1, s, 0, 0, 0);
      s_acc[t] = s;
    }
    __builtin_amdgcn_s_setprio(0);

    // P^T tile: exp, pack key-pairs, 8B stores into PT[q=col][key] (stride 72)
#pragma unroll
    for (int t = 0; t < 4; ++t) {
      float p0 = __expf(s_acc[t][0]);
      float p1 = __expf(s_acc[t][1]);
      float p2 = __expf(s_acc[t][2]);
      float p3 = __expf(s_acc[t][3]);
      l_lane += (p0 + p1) + (p2 + p3);
      uint2 u;
      u.x = (uint_t)f2bf_rna(p0) | ((uint_t)f2bf_rna(p1) << 16);
      u.y = (uint_t)f2bf_rna(p2) | ((uint_t)f2bf_rna(p3) << 16);
      *(uint2*)&Psw[col * 72 + t * 16 + quad * 4] = u;
    }

    // O += P . V   (read side identical to r0)
    __builtin_amdgcn_s_setprio(1);
#pragma unroll
    for (int kk = 0; kk < 2; ++kk) {
      short8 ap = *(const short8*)&Psw[col * 72 + kk * 32 + quad * 8];
#pragma unroll
      for (int t = 0; t < 4; ++t) {
        short8 bv = *(const short8*)&Vs[buf][(t * 16 + col) * 64 + (((kk * 4 + quad) ^ (col & 7)) * 8)];
        o_acc[t] = __builtin_amdgcn_mfma_f32_16x16x32_bf16(ap, bv, o_acc[t], 0, 0, 0);
      }
    }
    __builtin_amdgcn_s_setprio(0);

    __syncthreads();   // drains DMA (vmcnt 0) + all waves done with buf
  }
#undef STAGE

  // ---- softmax denominator: sum across the 4 quads holding q = col
  l_lane += __shfl_xor(l_lane, 16);
  l_lane += __shfl_xor(l_lane, 32);
  float invl = 1.0f / l_lane;          // inv denominator for q = col

  // normalize O, write attended rows [q][ic] into wave-private Ps rows
  // (same-wave DS ordering -> no barrier). o_acc rows are q = quad*4+r.
#pragma unroll
  for (int r = 0; r < 4; ++r) {
    float iv = __shfl(invl, (lane & 48) | (quad * 4 + r));
    int prow = (quad * 4 + r) * 72;
#pragma unroll
    for (int t = 0; t < 4; ++t)
      Psw[prow + t * 16 + col] = f2bf(o_acc[t][r] * iv);
  }

  // ---- fused output conv: D[p=16 per wave][o=256] + residual
  short8 ap0 = *(const short8*)&Psw[col * 72 + quad * 8];
  short8 ap1 = *(const short8*)&Psw[col * 72 + 32 + quad * 8];
  const uint4* W16 = (const uint4*)Wbf2;
  int pbase = qt * 64 + wave * 16 + quad * 4;
#pragma unroll
  for (int ot = 0; ot < 16; ++ot) {
    float bvv = W_b[ot * 16 + col];
    float4v c = {bvv, bvv, bvv, bvv};
    uint4 w0 = W16[quad * 256 + ot * 16 + col];
    uint4 w1 = W16[(4 + quad) * 256 + ot * 16 + col];
    c = __builtin_amdgcn_mfma_f32_16x16x32_bf16(ap0, *(const short8*)&w0, c, 0, 0, 0);
    c = __builtin_amdgcn_mfma_f32_16x16x32_bf16(ap1, *(const short8*)&w1, c, 0, 0, 0);
    size_t idx = ((size_t)(b * CC + ot * 16 + col)) * NPIX + pbase;
    float4 xv = *(const float4*)&x[idx];
    float4 ov;
    ov.x = c[0] + xv.x;
    ov.y = c[1] + xv.y;
    ov.z = c[2] + xv.z;
    ov.w = c[3] + xv.w;
    *(float4*)&out[idx] = ov;
  }
}

// ---------------------------------------------------------------------------
extern "C" void kernel_launch(void* const* d_in, const int* in_sizes, int n_in,
                              void* d_out, int out_size, void* d_ws, size_t ws_size,
                              hipStream_t stream) {
  const float* x       = (const float*)d_in[0];
  const float* g_w     = (const float*)d_in[1];
  const float* g_b     = (const float*)d_in[2];
  const float* theta_w = (const float*)d_in[3];
  const float* theta_b = (const float*)d_in[4];
  const float* phi_w   = (const float*)d_in[5];
  const float* phi_b   = (const float*)d_in[6];
  const float* W_w     = (const float*)d_in[7];
  const float* W_b     = (const float*)d_in[8];
  (void)in_sizes; (void)n_in; (void)out_size; (void)ws_size;

  char* ws = (char*)d_ws;
  ushort_t* wA2     = (ushort_t*)(ws + 0);         // 96KB bf16 [32][192][8]
  ushort_t* Wbf2    = (ushort_t*)(ws + 98304);     // 32KB bf16 [8][256][8]
  float*    biasAll = (float*)(ws + 131072);       // 768B
  ushort_t* qbuf    = (ushort_t*)(ws + 262144);    // 4MB bf16 [8][4096][64]
  ushort_t* kTbuf   = (ushort_t*)(ws + 4456448);   // 1MB bf16 [8][1024][64]
  ushort_t* vTbuf   = (ushort_t*)(ws + 5505024);   // 1MB bf16 [8][64][1024]
  float* out = (float*)d_out;

  prep_kernel<<<257, 256, 0, stream>>>(theta_w, phi_w, g_w, W_w,
                                       theta_b, phi_b, g_b,
                                       wA2, Wbf2, biasAll);
  qkv_kernel<<<512, 256, 0, stream>>>(x, wA2, biasAll, qbuf, kTbuf, vTbuf);
  attn_out_kernel<<<512, 256, 0, stream>>>(qbuf, kTbuf, vTbuf, Wbf2, W_b, x, out);
}